// Round 2
// baseline (1176.487 us; speedup 1.0000x reference)
//
#include <hip/hip_runtime.h>
#include <math.h>

#define NTT 27
#define NCC 128
#define K1 324      // 27 * 12
#define N1 256
#define N2 128
#define RT 32       // rows (c) per encoder1 block
#define KC1 12      // K-chunk for W1 (324 = 27*12)
#define NCH1 27
#define KC2 32      // K-chunk for W2 (256 = 8*32)
#define NCH2 8

// -------------------- encoder1: fv gather -> GEMM1(relu) -> GEMM2 -> h2 ----
// h2 layout: [b][m][a][c]  (channel-major so pooling reads are contiguous)
__global__ __launch_bounds__(256) void encoder1_kernel(
    const float* __restrict__ f0, const float* __restrict__ f1,
    const float* __restrict__ f2, const float* __restrict__ f3,
    const float* __restrict__ W1, const float* __restrict__ b1,
    const float* __restrict__ W2, const float* __restrict__ b2,
    float* __restrict__ h2)
{
    // LDS plan (floats):
    //  phase A: fvs [32][324] = 10368   | w1s [12][256] = 3072  @ 10368
    //  phase B: o1s [32][256] = 8192    | w2s [32][128] = 4096  @ 8192
    //  epilog : stile [32][132] = 4224  (reuses o1s region)
    __shared__ float smem[13440];   // 53760 B -> 2 blocks/CU
    float* fvs   = smem;
    float* w1s   = smem + RT * K1;
    float* o1s   = smem;
    float* w2s   = smem + RT * N1;
    float* stile = smem;

    const int tid = threadIdx.x;
    const int bid = blockIdx.x;
    const int b   = bid >> 9;           // 128 a * 4 c-chunks = 512 blocks / sample
    const int rem = bid & 511;
    const int a   = rem >> 2;
    const int c0  = (rem & 3) * RT;

    // ---- gather fv tile [32 rows][324]: 27*4 segments of 96 contiguous
    // floats (24 float4 each; 16B-aligned since base_bt%4==0, c0*3%4==0).
    // LDS dest is a stride-324 scatter -> scalar writes.
    {
        const int base_bt = ((b * NTT) * NCC + a) * NCC * 3 + c0 * 3;
        for (int idx = tid; idx < NTT * 4 * 24; idx += 256) {
            int seg = idx / 24;             // t*4 + src
            int q   = idx - seg * 24;       // float4 index within 96-float segment
            int t   = seg >> 2, src = seg & 3;
            const float* sp = (src == 0) ? f0 : (src == 1) ? f1 : (src == 2) ? f2 : f3;
            float4 v = *(const float4*)(sp + base_bt + t * (NCC * NCC * 3) + q * 4);
            const float vv[4] = {v.x, v.y, v.z, v.w};
            #pragma unroll
            for (int e = 0; e < 4; ++e) {
                int f = q * 4 + e;          // = r*3 + comp
                int r = f / 3, comp = f - r * 3;
                fvs[r * K1 + t * 12 + src * 3 + comp] = vv[e];
            }
        }
    }

    // ---- GEMM1: 32 rows x 256 cols, thread = 8 rows x 4 cols
    const int jg = tid & 63, rg = tid >> 6;
    const int j0 = jg * 4, r0 = rg * 8;
    float acc1[8][4];
    #pragma unroll
    for (int r = 0; r < 8; ++r)
        #pragma unroll
        for (int j = 0; j < 4; ++j) acc1[r][j] = 0.f;

    for (int kc = 0; kc < NCH1; ++kc) {
        {   // stage W1 chunk [12][256] = 768 float4, 3 per thread
            const float4* g = (const float4*)(W1 + kc * KC1 * N1);
            float4* s = (float4*)w1s;
            #pragma unroll
            for (int i = 0; i < 3; ++i) s[tid + i * 256] = g[tid + i * 256];
        }
        __syncthreads();
        const int kb = kc * KC1;
        #pragma unroll
        for (int k = 0; k < KC1; k += 4) {
            float areg[8][4];
            #pragma unroll
            for (int r = 0; r < 8; ++r) {
                float4 v = *(const float4*)&fvs[(r0 + r) * K1 + kb + k];
                areg[r][0] = v.x; areg[r][1] = v.y; areg[r][2] = v.z; areg[r][3] = v.w;
            }
            #pragma unroll
            for (int kk = 0; kk < 4; ++kk) {
                float4 w = *(const float4*)&w1s[(k + kk) * N1 + j0];
                #pragma unroll
                for (int r = 0; r < 8; ++r) {
                    acc1[r][0] = fmaf(areg[r][kk], w.x, acc1[r][0]);
                    acc1[r][1] = fmaf(areg[r][kk], w.y, acc1[r][1]);
                    acc1[r][2] = fmaf(areg[r][kk], w.z, acc1[r][2]);
                    acc1[r][3] = fmaf(areg[r][kk], w.w, acc1[r][3]);
                }
            }
        }
        __syncthreads();
    }

    // bias + relu -> o1s (overwrites fvs region; all fvs reads are behind barrier)
    {
        float4 bb = *(const float4*)&b1[j0];
        #pragma unroll
        for (int r = 0; r < 8; ++r) {
            float4 o;
            o.x = fmaxf(acc1[r][0] + bb.x, 0.f);
            o.y = fmaxf(acc1[r][1] + bb.y, 0.f);
            o.z = fmaxf(acc1[r][2] + bb.z, 0.f);
            o.w = fmaxf(acc1[r][3] + bb.w, 0.f);
            *(float4*)&o1s[(r0 + r) * N1 + j0] = o;
        }
    }

    // ---- GEMM2: 32 rows x 128 cols, thread = 4 rows x 4 cols
    const int mg = tid & 31, rg2 = tid >> 5;
    const int m0 = mg * 4, rr0 = rg2 * 4;
    float acc2[4][4];
    #pragma unroll
    for (int r = 0; r < 4; ++r)
        #pragma unroll
        for (int j = 0; j < 4; ++j) acc2[r][j] = 0.f;

    for (int kc = 0; kc < NCH2; ++kc) {
        {   // stage W2 chunk [32][128] = 1024 float4, 4 per thread
            const float4* g = (const float4*)(W2 + kc * KC2 * N2);
            float4* s = (float4*)w2s;
            #pragma unroll
            for (int i = 0; i < 4; ++i) s[tid + i * 256] = g[tid + i * 256];
        }
        __syncthreads();
        const int kb = kc * KC2;
        #pragma unroll
        for (int k = 0; k < KC2; k += 4) {
            float areg[4][4];
            #pragma unroll
            for (int r = 0; r < 4; ++r) {
                float4 v = *(const float4*)&o1s[(rr0 + r) * N1 + kb + k];
                areg[r][0] = v.x; areg[r][1] = v.y; areg[r][2] = v.z; areg[r][3] = v.w;
            }
            #pragma unroll
            for (int kk = 0; kk < 4; ++kk) {
                float4 w = *(const float4*)&w2s[(k + kk) * N2 + m0];
                #pragma unroll
                for (int r = 0; r < 4; ++r) {
                    acc2[r][0] = fmaf(areg[r][kk], w.x, acc2[r][0]);
                    acc2[r][1] = fmaf(areg[r][kk], w.y, acc2[r][1]);
                    acc2[r][2] = fmaf(areg[r][kk], w.z, acc2[r][2]);
                    acc2[r][3] = fmaf(areg[r][kk], w.w, acc2[r][3]);
                }
            }
        }
        __syncthreads();
    }

    // epilogue: bias, transpose tile in LDS, coalesced channel-major store
    {
        float4 bb = *(const float4*)&b2[m0];
        #pragma unroll
        for (int r = 0; r < 4; ++r) {
            float4 o;
            o.x = acc2[r][0] + bb.x;
            o.y = acc2[r][1] + bb.y;
            o.z = acc2[r][2] + bb.z;
            o.w = acc2[r][3] + bb.w;
            *(float4*)&stile[(rr0 + r) * 132 + m0] = o;   // stile[c'][m], pad 132
        }
    }
    __syncthreads();
    {
        const int out_base = b * (N2 * NCC * NCC) + a * NCC + c0;
        for (int i = tid; i < RT * N2; i += 256) {
            int cc2 = i & 31, m = i >> 5;
            h2[out_base + m * (NCC * NCC) + cc2] = stile[cc2 * 132 + m];
        }
    }
}

// -------------------- pooling: 8 invariants per (b, m) ---------------------
__global__ __launch_bounds__(256) void pool_kernel(const float* __restrict__ h2,
                                                   float* __restrict__ feat)
{
    __shared__ float xs[16384];   // 64 KB, swizzled: (a,c) at xs[a*128 + (c ^ (a&31))]
    const int tid = threadIdx.x;
    const int bm = blockIdx.x;    // b*128 + m
    const float* x = h2 + (size_t)bm * 16384;

    float s1 = 0.f, s4 = 0.f;
    for (int i = tid; i < 16384; i += 256) {
        float v = x[i];
        int aa = i >> 7, cc = i & 127;
        xs[aa * 128 + (cc ^ (aa & 31))] = v;
        s1 += v;
        s4 = fmaf(v, v, s4);
    }
    __syncthreads();

    const int i2 = tid >> 1, hh = tid & 1;   // pair (2i,2i+1) handles index i
    float rp = 0.f;
    #pragma unroll 4
    for (int j = 0; j < 64; ++j) {
        int cc = hh * 64 + j;
        rp += xs[i2 * 128 + (cc ^ (i2 & 31))];
    }
    float rowv = rp + __shfl_xor(rp, 1, 64);

    float cp = 0.f;
    #pragma unroll 4
    for (int j = 0; j < 64; ++j) {
        int aa = hh * 64 + j;
        cp += xs[aa * 128 + (i2 ^ (aa & 31))];
    }
    float colv = cp + __shfl_xor(cp, 1, 64);

    float d = xs[i2 * 128 + (i2 ^ (i2 & 31))];

    float s5 = 0.f;
    for (int i = tid; i < 16384; i += 256) {
        int aa = i >> 7, cc = i & 127;
        float v1 = xs[aa * 128 + (cc ^ (aa & 31))];
        float v2 = xs[cc * 128 + (aa ^ (cc & 31))];
        s5 = fmaf(v1, v2, s5);
    }

    float s[8];
    s[0] = d * 0.5f;            // each index i held by 2 threads -> halve
    s[1] = s1;
    s[2] = d * d * 0.5f;
    s[3] = d * rowv * 0.5f;
    s[4] = s4;
    s[5] = s5;
    s[6] = rowv * rowv * 0.5f;
    s[7] = rowv * colv * 0.5f;

    __syncthreads();            // done reading xs; reuse as reduction scratch
    #pragma unroll
    for (int off = 32; off > 0; off >>= 1)
        #pragma unroll
        for (int q = 0; q < 8; ++q) s[q] += __shfl_down(s[q], off, 64);

    const int wid = tid >> 6;
    if ((tid & 63) == 0) {
        #pragma unroll
        for (int q = 0; q < 8; ++q) xs[wid * 8 + q] = s[q];
    }
    __syncthreads();
    if (tid == 0) {
        const float den[8] = {128.f, 16384.f, 128.f, 16384.f,
                              16384.f, 16384.f, 2097152.f, 2097152.f};
        const int b = bm >> 7, m = bm & 127;
        #pragma unroll
        for (int q = 0; q < 8; ++q) {
            float v = (xs[q] + xs[8 + q] + xs[16 + q] + xs[24 + q]) / den[q];
            float vl = copysignf(log1pf(fabsf(v)), v) * 0.1f;
            feat[b * 1024 + q * 128 + m] = vl;
        }
    }
}

// -------------------- head: relu(feat@W3+b3)@W4+b4, tanh*8 -----------------
__global__ __launch_bounds__(256) void head_kernel(
    const float* __restrict__ feat, const float* __restrict__ W3,
    const float* __restrict__ b3, const float* __restrict__ W4,
    const float* __restrict__ b4, float* __restrict__ out)
{
    __shared__ float fs[1024];
    __shared__ float red[8];
    const int tid = threadIdx.x, b = blockIdx.x;
    for (int i = tid; i < 1024; i += 256) fs[i] = feat[b * 1024 + i];
    __syncthreads();
    float acc = b3[tid];
    #pragma unroll 8
    for (int k = 0; k < 1024; ++k) acc = fmaf(fs[k], W3[k * 256 + tid], acc);
    float g = fmaxf(acc, 0.f);
    float p0 = g * W4[tid * 2 + 0];
    float p1 = g * W4[tid * 2 + 1];
    #pragma unroll
    for (int off = 32; off > 0; off >>= 1) {
        p0 += __shfl_down(p0, off, 64);
        p1 += __shfl_down(p1, off, 64);
    }
    const int wid = tid >> 6;
    if ((tid & 63) == 0) { red[wid * 2] = p0; red[wid * 2 + 1] = p1; }
    __syncthreads();
    if (tid == 0) {
        float o0 = red[0] + red[2] + red[4] + red[6] + b4[0];
        float o1 = red[1] + red[3] + red[5] + red[7] + b4[1];
        out[b * 2 + 0] = tanhf(o0) * 8.f;
        out[b * 2 + 1] = tanhf(o1) * 8.f;
    }
}

extern "C" void kernel_launch(void* const* d_in, const int* in_sizes, int n_in,
                              void* d_out, int out_size, void* d_ws, size_t ws_size,
                              hipStream_t stream)
{
    const float* f0 = (const float*)d_in[0];
    const float* f1 = (const float*)d_in[1];
    const float* f2 = (const float*)d_in[2];
    const float* f3 = (const float*)d_in[3];
    const float* W1 = (const float*)d_in[4];
    const float* b1 = (const float*)d_in[5];
    const float* W2 = (const float*)d_in[6];
    const float* b2 = (const float*)d_in[7];
    const float* W3 = (const float*)d_in[8];
    const float* b3 = (const float*)d_in[9];
    const float* W4 = (const float*)d_in[10];
    const float* b4 = (const float*)d_in[11];

    float* h2   = (float*)d_ws;                       // 16*128*128*128 f32 = 128 MiB
    float* feat = h2 + (size_t)16 * 128 * 128 * 128;  // 16*1024 f32

    encoder1_kernel<<<16 * 128 * 4, 256, 0, stream>>>(f0, f1, f2, f3,
                                                      W1, b1, W2, b2, h2);
    pool_kernel<<<16 * 128, 256, 0, stream>>>(h2, feat);
    head_kernel<<<16, 256, 0, stream>>>(feat, W3, b3, W4, b4, (float*)d_out);
}

// Round 3
// 885.155 us; speedup vs baseline: 1.3291x; 1.3291x over previous
//
#include <hip/hip_runtime.h>
#include <math.h>

typedef _Float16 f16x8 __attribute__((ext_vector_type(8)));
typedef _Float16 f16x4 __attribute__((ext_vector_type(4)));
typedef float    f32x16 __attribute__((ext_vector_type(16)));

#define NTT 27
#define K1P 336          // 324 data + 1 bias + 11 zero (21 chunks of 16)
#define K2P 272          // 256 data + 1 bias + 15 zero (17 chunks of 16)
#define FVS 384          // fv LDS row stride in f16 (768 B, mult of 128 B)
#define O1S 320          // o1 LDS row stride in f16 (640 B, mult of 128 B)

__device__ __forceinline__ void f16split(float x, _Float16& h, _Float16& l) {
    h = (_Float16)x;
    l = (_Float16)((x - (float)h) * 2048.0f);   // scaled-lo: stays in normal range
}

// ---- prep: split+transpose weights, fold biases into extra k-column -------
__global__ __launch_bounds__(256) void prep_weights(
    const float* __restrict__ W1, const float* __restrict__ b1,
    const float* __restrict__ W2, const float* __restrict__ b2,
    _Float16* __restrict__ W1Th, _Float16* __restrict__ W1Tl,
    _Float16* __restrict__ W2Th, _Float16* __restrict__ W2Tl)
{
    int i = blockIdx.x * 256 + threadIdx.x;
    if (i < 256 * K1P) {
        int n = i / K1P, k = i - n * K1P;
        float x = (k < 324) ? W1[k * 256 + n] : ((k == 324) ? b1[n] : 0.f);
        _Float16 h, l; f16split(x, h, l);
        W1Th[i] = h; W1Tl[i] = l;
    } else {
        int j = i - 256 * K1P;
        if (j < 128 * K2P) {
            int m = j / K2P, k = j - m * K2P;
            float x = (k < 256) ? W2[k * 128 + m] : ((k == 256) ? b2[m] : 0.f);
            _Float16 h, l; f16split(x, h, l);
            W2Th[j] = h; W2Tl[j] = l;
        }
    }
}

// ---- encoder1: gather -> split-f16 MFMA GEMM1(relu) -> GEMM2 -> h2 --------
// h2 layout: [b][m][a][c] (channel-major for pooling)
__global__ __launch_bounds__(256) void encoder1_kernel(
    const float* __restrict__ f0, const float* __restrict__ f1,
    const float* __restrict__ f2, const float* __restrict__ f3,
    const _Float16* __restrict__ W1Th, const _Float16* __restrict__ W1Tl,
    const _Float16* __restrict__ W2Th, const _Float16* __restrict__ W2Tl,
    float* __restrict__ h2)
{
    // 49152 B LDS -> 3 blocks/CU. fv planes [32][384]; o1 planes [32][320] alias.
    __shared__ _Float16 smem[24576];
    _Float16* fvh = smem;
    _Float16* fvl = smem + 12288;
    _Float16* o1h = smem;            // alias (behind barrier)
    _Float16* o1l = smem + 10240;

    const int tid = threadIdx.x;
    const int bid = blockIdx.x;
    const int b   = bid >> 9;
    const int rem = bid & 511;
    const int a   = rem >> 2;
    const int c0  = (rem & 3) * 32;

    // ---- gather fv tile [32 r][324 k] as float4, split to f16 hi/lo planes
    {
        const int base_bt = ((b * NTT) * 128 + a) * 384 + c0 * 3;
        for (int idx = tid; idx < NTT * 4 * 24; idx += 256) {
            int seg = idx / 24;             // t*4 + src
            int q   = idx - seg * 24;       // float4 within 96-float segment
            int t   = seg >> 2, src = seg & 3;
            const float* sp = (src == 0) ? f0 : (src == 1) ? f1 : (src == 2) ? f2 : f3;
            float4 v = *(const float4*)(sp + base_bt + t * 49152 + q * 4);
            float vv[4] = {v.x, v.y, v.z, v.w};
            #pragma unroll
            for (int e = 0; e < 4; ++e) {
                int f = q * 4 + e;          // = r*3 + comp
                int r = f / 3, comp = f - r * 3;
                int col = t * 12 + src * 3 + comp;
                int u = (r * FVS + col) ^ ((r & 7) << 3);
                _Float16 h, l; f16split(vv[e], h, l);
                fvh[u] = h; fvl[u] = l;
            }
        }
        // bias column (k=324 -> 1.0) + zero pad k=325..335
        for (int i = tid; i < 32 * 12; i += 256) {
            int r = i / 12, col = 324 + (i - (i / 12) * 12);
            int u = (r * FVS + col) ^ ((r & 7) << 3);
            fvh[u] = (col == 324) ? (_Float16)1.0f : (_Float16)0.0f;
            fvl[u] = (_Float16)0.0f;
        }
    }
    __syncthreads();

    const int lane = tid & 63;
    const int w    = tid >> 6;        // wave id 0..3
    const int lr   = lane & 31;       // A-row / B-col index
    const int lq   = lane >> 5;       // k-group
    const int swz  = (lr & 7) << 3;   // 16B-granular XOR swizzle (f16 units)

    // ---- GEMM1: O1T[256 n][32 r] = W1T x fvT, split-f16 dual accumulators
    f32x16 accm[2], accx[2];
    #pragma unroll
    for (int e = 0; e < 16; ++e) {
        accm[0][e] = 0.f; accm[1][e] = 0.f;
        accx[0][e] = 0.f; accx[1][e] = 0.f;
    }
    const int fvrow = lr * FVS;
    #pragma unroll 3
    for (int kc = 0; kc < 21; ++kc) {
        const int col = kc * 16 + lq * 8;
        f16x8 bh = *(const f16x8*)&fvh[(fvrow + col) ^ swz];
        f16x8 bl = *(const f16x8*)&fvl[(fvrow + col) ^ swz];
        #pragma unroll
        for (int t = 0; t < 2; ++t) {
            const int n = (w * 2 + t) * 32 + lr;
            f16x8 ah = *(const f16x8*)(W1Th + n * K1P + col);
            f16x8 al = *(const f16x8*)(W1Tl + n * K1P + col);
            accm[t] = __builtin_amdgcn_mfma_f32_32x32x16_f16(ah, bh, accm[t], 0, 0, 0);
            accx[t] = __builtin_amdgcn_mfma_f32_32x32x16_f16(ah, bl, accx[t], 0, 0, 0);
            accx[t] = __builtin_amdgcn_mfma_f32_32x32x16_f16(al, bh, accx[t], 0, 0, 0);
        }
    }
    __syncthreads();   // all fv reads done; o1 planes alias fv region

    // ---- epilogue 1: combine, relu, split -> o1 planes (8B f16x4 stores)
    const int o1row = lr * O1S;
    #pragma unroll
    for (int t = 0; t < 2; ++t) {
        #pragma unroll
        for (int g = 0; g < 4; ++g) {
            const int n0 = (w * 2 + t) * 32 + g * 8 + lq * 4;
            f16x4 ph, pl;
            #pragma unroll
            for (int e = 0; e < 4; ++e) {
                float v = accm[t][g * 4 + e] + accx[t][g * 4 + e] * 4.8828125e-4f;
                v = fmaxf(v, 0.f);
                _Float16 h, l; f16split(v, h, l);
                ph[e] = h; pl[e] = l;
            }
            int u = (o1row + n0) ^ swz;
            *(f16x4*)&o1h[u] = ph;
            *(f16x4*)&o1l[u] = pl;
        }
    }
    // bias column (k=256 -> 1.0) + zero pad k=257..271
    for (int i = tid; i < 32 * 16; i += 256) {
        int r = i >> 4, col = 256 + (i & 15);
        int u = (r * O1S + col) ^ ((r & 7) << 3);
        o1h[u] = (col == 256) ? (_Float16)1.0f : (_Float16)0.0f;
        o1l[u] = (_Float16)0.0f;
    }
    __syncthreads();

    // ---- GEMM2: O2T[128 m][32 r] = W2T x O1T
    f32x16 cm, cx;
    #pragma unroll
    for (int e = 0; e < 16; ++e) { cm[e] = 0.f; cx[e] = 0.f; }
    #pragma unroll 3
    for (int kc = 0; kc < 17; ++kc) {
        const int col = kc * 16 + lq * 8;
        f16x8 bh = *(const f16x8*)&o1h[(o1row + col) ^ swz];
        f16x8 bl = *(const f16x8*)&o1l[(o1row + col) ^ swz];
        const int m = w * 32 + lr;
        f16x8 ah = *(const f16x8*)(W2Th + m * K2P + col);
        f16x8 al = *(const f16x8*)(W2Tl + m * K2P + col);
        cm = __builtin_amdgcn_mfma_f32_32x32x16_f16(ah, bh, cm, 0, 0, 0);
        cx = __builtin_amdgcn_mfma_f32_32x32x16_f16(ah, bl, cx, 0, 0, 0);
        cx = __builtin_amdgcn_mfma_f32_32x32x16_f16(al, bh, cx, 0, 0, 0);
    }

    // ---- direct coalesced store: h2[b][m][a][c0+lr]
    {
        float* op = h2 + (size_t)b * 2097152 + (size_t)a * 128 + c0 + lr;
        #pragma unroll
        for (int reg = 0; reg < 16; ++reg) {
            int m = w * 32 + (reg & 3) + (reg >> 2) * 8 + lq * 4;
            op[(size_t)m * 16384] = cm[reg] + cx[reg] * 4.8828125e-4f;
        }
    }
}

// -------------------- pooling: 8 invariants per (b, m) ---------------------
__global__ __launch_bounds__(256) void pool_kernel(const float* __restrict__ h2,
                                                   float* __restrict__ feat)
{
    __shared__ float xs[16384];   // 64 KB, swizzled: (a,c) at xs[a*128 + (c ^ (a&31))]
    const int tid = threadIdx.x;
    const int bm = blockIdx.x;    // b*128 + m
    const float* x = h2 + (size_t)bm * 16384;

    float s1 = 0.f, s4 = 0.f;
    for (int i = tid; i < 16384; i += 256) {
        float v = x[i];
        int aa = i >> 7, cc = i & 127;
        xs[aa * 128 + (cc ^ (aa & 31))] = v;
        s1 += v;
        s4 = fmaf(v, v, s4);
    }
    __syncthreads();

    const int i2 = tid >> 1, hh = tid & 1;   // pair (2i,2i+1) handles index i
    float rp = 0.f;
    #pragma unroll 4
    for (int j = 0; j < 64; ++j) {
        int cc = hh * 64 + j;
        rp += xs[i2 * 128 + (cc ^ (i2 & 31))];
    }
    float rowv = rp + __shfl_xor(rp, 1, 64);

    float cp = 0.f;
    #pragma unroll 4
    for (int j = 0; j < 64; ++j) {
        int aa = hh * 64 + j;
        cp += xs[aa * 128 + (i2 ^ (aa & 31))];
    }
    float colv = cp + __shfl_xor(cp, 1, 64);

    float d = xs[i2 * 128 + (i2 ^ (i2 & 31))];

    float s5 = 0.f;
    for (int i = tid; i < 16384; i += 256) {
        int aa = i >> 7, cc = i & 127;
        float v1 = xs[aa * 128 + (cc ^ (aa & 31))];
        float v2 = xs[cc * 128 + (aa ^ (cc & 31))];
        s5 = fmaf(v1, v2, s5);
    }

    float s[8];
    s[0] = d * 0.5f;            // each index held by 2 threads -> halve
    s[1] = s1;
    s[2] = d * d * 0.5f;
    s[3] = d * rowv * 0.5f;
    s[4] = s4;
    s[5] = s5;
    s[6] = rowv * rowv * 0.5f;
    s[7] = rowv * colv * 0.5f;

    __syncthreads();            // done reading xs; reuse as reduction scratch
    #pragma unroll
    for (int off = 32; off > 0; off >>= 1)
        #pragma unroll
        for (int q = 0; q < 8; ++q) s[q] += __shfl_down(s[q], off, 64);

    const int wid = tid >> 6;
    if ((tid & 63) == 0) {
        #pragma unroll
        for (int q = 0; q < 8; ++q) xs[wid * 8 + q] = s[q];
    }
    __syncthreads();
    if (tid == 0) {
        const float den[8] = {128.f, 16384.f, 128.f, 16384.f,
                              16384.f, 16384.f, 2097152.f, 2097152.f};
        const int b = bm >> 7, m = bm & 127;
        #pragma unroll
        for (int q = 0; q < 8; ++q) {
            float v = (xs[q] + xs[8 + q] + xs[16 + q] + xs[24 + q]) / den[q];
            float vl = copysignf(log1pf(fabsf(v)), v) * 0.1f;
            feat[b * 1024 + q * 128 + m] = vl;
        }
    }
}

// -------------------- head: relu(feat@W3+b3)@W4+b4, tanh*8 -----------------
__global__ __launch_bounds__(256) void head_kernel(
    const float* __restrict__ feat, const float* __restrict__ W3,
    const float* __restrict__ b3, const float* __restrict__ W4,
    const float* __restrict__ b4, float* __restrict__ out)
{
    __shared__ float fs[1024];
    __shared__ float red[8];
    const int tid = threadIdx.x, b = blockIdx.x;
    for (int i = tid; i < 1024; i += 256) fs[i] = feat[b * 1024 + i];
    __syncthreads();
    float acc = b3[tid];
    #pragma unroll 8
    for (int k = 0; k < 1024; ++k) acc = fmaf(fs[k], W3[k * 256 + tid], acc);
    float g = fmaxf(acc, 0.f);
    float p0 = g * W4[tid * 2 + 0];
    float p1 = g * W4[tid * 2 + 1];
    #pragma unroll
    for (int off = 32; off > 0; off >>= 1) {
        p0 += __shfl_down(p0, off, 64);
        p1 += __shfl_down(p1, off, 64);
    }
    const int wid = tid >> 6;
    if ((tid & 63) == 0) { red[wid * 2] = p0; red[wid * 2 + 1] = p1; }
    __syncthreads();
    if (tid == 0) {
        float o0 = red[0] + red[2] + red[4] + red[6] + b4[0];
        float o1 = red[1] + red[3] + red[5] + red[7] + b4[1];
        out[b * 2 + 0] = tanhf(o0) * 8.f;
        out[b * 2 + 1] = tanhf(o1) * 8.f;
    }
}

extern "C" void kernel_launch(void* const* d_in, const int* in_sizes, int n_in,
                              void* d_out, int out_size, void* d_ws, size_t ws_size,
                              hipStream_t stream)
{
    const float* f0 = (const float*)d_in[0];
    const float* f1 = (const float*)d_in[1];
    const float* f2 = (const float*)d_in[2];
    const float* f3 = (const float*)d_in[3];
    const float* W1 = (const float*)d_in[4];
    const float* b1 = (const float*)d_in[5];
    const float* W2 = (const float*)d_in[6];
    const float* b2 = (const float*)d_in[7];
    const float* W3 = (const float*)d_in[8];
    const float* b3 = (const float*)d_in[9];
    const float* W4 = (const float*)d_in[10];
    const float* b4 = (const float*)d_in[11];

    float* h2   = (float*)d_ws;                       // 16*128*128*128 f32 = 128 MiB
    float* feat = h2 + (size_t)33554432;              // 16*1024 f32
    _Float16* W1Th = (_Float16*)(feat + 16384);
    _Float16* W1Tl = W1Th + 256 * K1P;
    _Float16* W2Th = W1Tl + 256 * K1P;
    _Float16* W2Tl = W2Th + 128 * K2P;

    prep_weights<<<472, 256, 0, stream>>>(W1, b1, W2, b2, W1Th, W1Tl, W2Th, W2Tl);
    encoder1_kernel<<<16 * 128 * 4, 256, 0, stream>>>(f0, f1, f2, f3,
                                                      W1Th, W1Tl, W2Th, W2Tl, h2);
    pool_kernel<<<16 * 128, 256, 0, stream>>>(h2, feat);
    head_kernel<<<16, 256, 0, stream>>>(feat, W3, b3, W4, b4, (float*)d_out);
}